// Round 6
// baseline (1750.588 us; speedup 1.0000x reference)
//
#include <hip/hip_runtime.h>
#include <stdint.h>

typedef __attribute__((ext_vector_type(8))) short short8;
typedef __attribute__((ext_vector_type(16))) float f32x16;
typedef __attribute__((ext_vector_type(4))) float f32x4;
typedef __attribute__((ext_vector_type(4))) unsigned short ushort4v;

union S8 { short8 v; unsigned short u[8]; };

static __device__ __forceinline__ unsigned short f2bf(float f) {
  union { float f; unsigned u; } v; v.f = f;
  unsigned r = v.u + 0x7fffu + ((v.u >> 16) & 1u);
  return (unsigned short)(r >> 16);
}

// ---------------- prep: W -> per-wave B-fragment images ----------------
// t = ((((c*8+g8)*32+kt)*2+ks)*8+tt)*64+lane ; tt = s*4+gt
// value = W_c[s][k = kt*32+ks*16+(lane>>5)*8+e][g = g8*128+gt*32+(lane&31)]
__global__ __launch_bounds__(256) void prep_w(const float* __restrict__ Wa,
                                              const float* __restrict__ Wb,
                                              const float* __restrict__ Wc,
                                              unsigned short* __restrict__ wfrag) {
  int t    = blockIdx.x * 256 + threadIdx.x;
  int lane = t & 63;
  int tt   = (t >> 6) & 7;
  int ks   = (t >> 9) & 1;
  int kt   = (t >> 10) & 31;
  int g8   = (t >> 15) & 7;
  int c    = t >> 18;
  const float* W = (c == 0) ? Wa : (c == 1) ? Wb : Wc;
  int s  = tt >> 2, gt = tt & 3;
  int g  = g8*128 + gt*32 + (lane & 31);
  int k0 = kt*32 + ks*16 + ((lane >> 5) * 8);
  const float* src = W + (size_t)s * 1048576 + (size_t)k0 * 1024 + g;
  unsigned short* dst = wfrag + (size_t)t * 8;
#pragma unroll
  for (int e = 0; e < 8; ++e) dst[e] = f2bf(src[(size_t)e * 1024]);
}

// ---------------- prep: x -> A-fragment image for one channel ----------------
// t = (((gid*32+kt)*2+ks)*2+h)*64+lane ; value = A[row = h*32 + (lane&31)][k]
__global__ __launch_bounds__(256) void prep_x(const float* __restrict__ x,
                                              const int* __restrict__ idxp,
                                              int c, unsigned short* __restrict__ ximg) {
  int t = blockIdx.x * 256 + threadIdx.x;
  int lane = t & 63;
  int h  = (t >> 6) & 1;
  int ks = (t >> 7) & 1;
  int kt = (t >> 8) & 31;
  int gid = t >> 13;
  int b = gid >> 3, v = gid & 7;
  int vv = h ? idxp[v] : v;
  const float* src = x + (size_t)(b*8 + vv) * 32768;
  int i = lane & 31;
  int k0 = kt*32 + ks*16 + ((lane >> 5) * 8);
  S8 pk;
  if (c == 0) {
#pragma unroll
    for (int e = 0; e < 8; ++e) pk.u[e] = f2bf(src[(size_t)(k0 + e)*32 + i]);
  } else {
    const float* sp = (c == 1) ? (src + i*1024 + k0)
                               : (src + (k0 >> 5)*1024 + i*32 + (k0 & 31));
    float4 u0 = *(const float4*)sp, u1 = *(const float4*)(sp + 4);
    pk.u[0]=f2bf(u0.x); pk.u[1]=f2bf(u0.y); pk.u[2]=f2bf(u0.z); pk.u[3]=f2bf(u0.w);
    pk.u[4]=f2bf(u1.x); pk.u[5]=f2bf(u1.y); pk.u[6]=f2bf(u1.z); pk.u[7]=f2bf(u1.w);
  }
  *(short8*)(ximg + (size_t)t * 8) = pk.v;
}

// ---------------- prep: softmax A, Aoff frags, diag, BN affine ----------------
__global__ __launch_bounds__(256) void prep_misc(
    const float* e0, const int* a0, const float* b0, const float* g0, const float* be0, const float* rm0, const float* rv0,
    const float* e1, const int* a1, const float* b1, const float* g1, const float* be1, const float* rm1, const float* rv1,
    const float* e2, const int* a2, const float* b2, const float* g2, const float* be2, const float* rm2, const float* rv2,
    unsigned short* __restrict__ aofrag, float* __restrict__ diagA,
    float* __restrict__ scale2, float* __restrict__ shift2) {
  __shared__ float A[64][64];
  int c = blockIdx.x;
  int tid = threadIdx.x;
  const float* ev = (c==0)?e0:(c==1)?e1:e2;
  const int*   ad = (c==0)?a0:(c==1)?a1:a2;
  const float* bb = (c==0)?b0:(c==1)?b1:b2;
  const float* gm = (c==0)?g0:(c==1)?g1:g2;
  const float* bt = (c==0)?be0:(c==1)?be1:be2;
  const float* rm = (c==0)?rm0:(c==1)?rm1:rm2;
  const float* rv = (c==0)?rv0:(c==1)?rv1:rv2;
  if (tid < 64) {
    int n = tid;
    float mx = -3.0e38f;
    for (int m = 0; m < 64; ++m) {
      float lg = (ad[n*64+m] > 0) ? ev[n*64+m] : -9.0e15f;
      A[n][m] = lg; mx = fmaxf(mx, lg);
    }
    float ssum = 0.f;
    for (int m = 0; m < 64; ++m) { float p = __expf(A[n][m] - mx); A[n][m] = p; ssum += p; }
    float inv = 1.f / ssum;
    for (int m = 0; m < 64; ++m) A[n][m] *= inv;
  }
  __syncthreads();
  if (tid < 64) diagA[c*64 + tid] = A[tid][tid];
  // Aoff in 32x32x16 A-frag layout: [nt(2)][ks(4)][lane(64)][8]
  for (int idx = tid; idx < 4096; idx += 256) {
    int e  = idx & 7;
    int l  = (idx >> 3) & 63;
    int ks = (idx >> 9) & 3;
    int nt = idx >> 11;
    int n = nt*32 + (l & 31);
    int m = ks*16 + ((l >> 5) * 8) + e;
    float vv = (m == n) ? 0.f : A[n][m];
    aofrag[c*4096 + idx] = f2bf(vv);
  }
  for (int g = tid; g < 1024; g += 256) {
    float sc = gm[g] * rsqrtf(rv[g] + 1e-5f);
    scale2[c*1024 + g] = sc;
    shift2[c*1024 + g] = bt[g] + (bb[g] - rm[g]) * sc;
  }
}

// ---------------- register loaders ----------------
static __device__ __forceinline__ void loadB4(short8 bdst[4], const char* wB, int kt, int ks) {
  const char* p = wB + (size_t)kt * 16384 + ks * 8192;
#pragma unroll
  for (int gt = 0; gt < 4; ++gt) bdst[gt] = *(const short8*)(p + gt*1024);
}

// a[ks*2+h]; row i0 = lane&31, k = kt*32 + ks*16 + lh8 + e
template<int CH, int IMG>
static __device__ __forceinline__ void loadAfr(short8 a[4], const char* aB,
                                               const float* __restrict__ v0,
                                               const float* __restrict__ v1,
                                               int i0, int lh8, int kt) {
  if (IMG) {
    const char* p = aB + (size_t)kt * 4096;
#pragma unroll
    for (int ks = 0; ks < 2; ++ks)
#pragma unroll
      for (int h = 0; h < 2; ++h)
        a[ks*2 + h] = *(const short8*)(p + ks*2048 + h*1024);
  } else {
#pragma unroll
    for (int ks = 0; ks < 2; ++ks)
#pragma unroll
      for (int h = 0; h < 2; ++h) {
        const float* src = h ? v1 : v0;
        int k0 = kt*32 + ks*16 + lh8;
        S8 pk;
        if (CH == 0) {
#pragma unroll
          for (int e = 0; e < 8; ++e) pk.u[e] = f2bf(src[(size_t)(k0 + e)*32 + i0]);
        } else {
          const float* sp = (CH == 1) ? (src + i0*1024 + k0)
                                      : (src + (k0 >> 5)*1024 + i0*32 + (k0 & 31));
          float4 u0 = *(const float4*)sp, u1 = *(const float4*)(sp + 4);
          pk.u[0]=f2bf(u0.x); pk.u[1]=f2bf(u0.y); pk.u[2]=f2bf(u0.z); pk.u[3]=f2bf(u0.w);
          pk.u[4]=f2bf(u1.x); pk.u[5]=f2bf(u1.y); pk.u[6]=f2bf(u1.z); pk.u[7]=f2bf(u1.w);
        }
        a[ks*2 + h] = pk.v;
      }
  }
}

static __device__ __forceinline__ void mfma8(short8 a0, short8 a1, const short8 b[4],
                                             f32x16 (&acc)[2][4]) {
#pragma unroll
  for (int gt = 0; gt < 4; ++gt) {
    acc[0][gt] = __builtin_amdgcn_mfma_f32_32x32x16_bf16(a0, b[gt], acc[0][gt], 0, 0, 0);
    acc[1][gt] = __builtin_amdgcn_mfma_f32_32x32x16_bf16(a1, b[gt], acc[1][gt], 0, 0, 0);
  }
}

// ---------------- main fused channel kernel: all-register, barrier-free K-loop ----------------
// block: 128 m-rows (2 graphs) x [128 g x 2 s]; wave (wm,sn) = graph wm, weight-half sn
// grid: bid = mp*8 + g8  (g8 = XCD affinity -> W image L2-resident)
template<int CH, int IMG>
__global__ __launch_bounds__(256, 2) void gconv(
    const float* __restrict__ x, const int* __restrict__ idxp,
    const unsigned short* __restrict__ wimg, const unsigned short* __restrict__ ximg,
    const unsigned short* __restrict__ aofrag,
    const float* __restrict__ diagA, const float* __restrict__ scale2,
    const float* __restrict__ shift2, float* __restrict__ out) {
  __shared__ alignas(128) char lds[65536];   // epilogue only: H1 [0,32K) + H0x [32K,64K)
  int tid = threadIdx.x, lane = tid & 63, wave = tid >> 6;
  int l31 = lane & 31, lh = lane >> 5;
  int wm = wave >> 1, sn = wave & 1;
  int bid = blockIdx.x;
  int g8 = bid & 7, mp = bid >> 3;
  int graphA = mp*2;
  int gid = graphA + wm;
  int b = gid >> 3, v = gid & 7;
  const float* v0 = x + (size_t)(b*8 + v) * 32768;
  const float* v1 = x + (size_t)(b*8 + idxp[v]) * 32768;
  const char* wB = (const char*)wimg + (size_t)g8 * 524288 + sn*4096 + lane*16;
  const char* aB = (const char*)ximg + (size_t)gid * 131072 + lane*16;
  int i0 = l31, lh8 = lh*8;

  f32x16 acc[2][4];
#pragma unroll
  for (int mt = 0; mt < 2; ++mt)
#pragma unroll
    for (int gt = 0; gt < 4; ++gt)
#pragma unroll
      for (int r = 0; r < 16; ++r) acc[mt][gt][r] = 0.f;

  short8 aC[4], aN[4], b0[4], b1[4];
  loadAfr<CH, IMG>(aC, aB, v0, v1, i0, lh8, 0);
  loadB4(b0, wB, 0, 0);
  loadB4(b1, wB, 0, 1);
  loadAfr<CH, IMG>(aN, aB, v0, v1, i0, lh8, 1);

  // body(kt) computes kt (aC) and kt+1 (aN); b regs rotate kt -> kt+1 -> kt+2
#pragma unroll 1
  for (int kt = 0; kt < 30; kt += 2) {
    mfma8(aC[0], aC[1], b0, acc);
    loadB4(b0, wB, kt + 1, 0);
    mfma8(aC[2], aC[3], b1, acc);
    loadB4(b1, wB, kt + 1, 1);
    loadAfr<CH, IMG>(aC, aB, v0, v1, i0, lh8, kt + 2);
    mfma8(aN[0], aN[1], b0, acc);
    loadB4(b0, wB, kt + 2, 0);
    mfma8(aN[2], aN[3], b1, acc);
    loadB4(b1, wB, kt + 2, 1);
    loadAfr<CH, IMG>(aN, aB, v0, v1, i0, lh8, kt + 3);
  }
  // tail: kt = 30, 31
  mfma8(aC[0], aC[1], b0, acc);
  loadB4(b0, wB, 31, 0);
  mfma8(aC[2], aC[3], b1, acc);
  loadB4(b1, wB, 31, 1);
  mfma8(aN[0], aN[1], b0, acc);
  mfma8(aN[2], aN[3], b1, acc);

  // ---- epilogue (verified r4/r5 structure) ----
  // sn==1 waves write H1 (bf16 col-major, swizzled); sn==0 waves export H0 g-half-1 (f32)
  if (sn == 1) {
    char* basep = lds + wm*16384;
#pragma unroll
    for (int gt = 0; gt < 4; ++gt) {
      int col = gt*32 + l31;
      char* cb = basep + col*128;
      int cs = (col & 7) << 4;
#pragma unroll
      for (int mt2 = 0; mt2 < 2; ++mt2)
#pragma unroll
        for (int j = 0; j < 4; ++j) {
          ushort4v pk;
          pk.x = f2bf(acc[mt2][gt][4*j+0]);
          pk.y = f2bf(acc[mt2][gt][4*j+1]);
          pk.z = f2bf(acc[mt2][gt][4*j+2]);
          pk.w = f2bf(acc[mt2][gt][4*j+3]);
          int r2 = mt2*64 + j*16 + lh*8;
          *(ushort4v*)(cb + (r2 ^ cs)) = pk;
        }
    }
  } else {
    char* ebase = lds + 32768 + wm*16384;
#pragma unroll
    for (int mt2 = 0; mt2 < 2; ++mt2)
#pragma unroll
      for (int t2 = 0; t2 < 2; ++t2)
#pragma unroll
        for (int q4 = 0; q4 < 4; ++q4)
          *(f32x4*)(ebase + (size_t)(((mt2*2 + t2)*4) + q4)*1024 + lane*16) =
              ((const f32x4*)&acc[mt2][2 + t2])[q4];
  }
  __syncthreads();

  // agg = Aoff @ H1 for (graph wm, g-half sn)
  f32x16 agg[2][2];
#pragma unroll
  for (int nta = 0; nta < 2; ++nta)
#pragma unroll
    for (int gl = 0; gl < 2; ++gl)
#pragma unroll
      for (int r = 0; r < 16; ++r) agg[nta][gl][r] = 0.f;

#pragma unroll
  for (int ks = 0; ks < 4; ++ks) {
#pragma unroll
    for (int gl = 0; gl < 2; ++gl) {
      int col = (sn*2 + gl)*32 + l31;
      int cs = (col & 7) << 4;
      short8 hf = *(const short8*)(lds + wm*16384 + col*128 + ((ks*32 + lh*16) ^ cs));
#pragma unroll
      for (int nta = 0; nta < 2; ++nta) {
        short8 aof = *(const short8*)((const char*)aofrag + (size_t)((nta*4 + ks)*64 + lane)*16);
        agg[nta][gl] = __builtin_amdgcn_mfma_f32_32x32x16_bf16(aof, hf, agg[nta][gl], 0, 0, 0);
      }
    }
  }

  // H0 for my g-half
  f32x16 h0[2][2];
  if (sn == 0) {
    h0[0][0] = acc[0][0]; h0[0][1] = acc[0][1];
    h0[1][0] = acc[1][0]; h0[1][1] = acc[1][1];
  } else {
    const char* ebase = lds + 32768 + wm*16384;
#pragma unroll
    for (int mt2 = 0; mt2 < 2; ++mt2)
#pragma unroll
      for (int t2 = 0; t2 < 2; ++t2)
#pragma unroll
        for (int q4 = 0; q4 < 4; ++q4)
          ((f32x4*)&h0[mt2][t2])[q4] =
              *(const f32x4*)(ebase + (size_t)(((mt2*2 + t2)*4) + q4)*1024 + lane*16);
  }

  // combine + BN + ReLU + pair-mean + scatter
  size_t obase = (size_t)gid * 32768;
#pragma unroll
  for (int gl = 0; gl < 2; ++gl) {
    int g = g8*128 + sn*64 + gl*32 + l31;
    float sc = scale2[g], sh = shift2[g];
#pragma unroll
    for (int j = 0; j < 4; ++j) {
      int i00 = j*8 + lh*4;
      float4 dA = *(const float4*)(diagA + i00);
      float4 dB = *(const float4*)(diagA + 32 + i00);
      float res[4];
#pragma unroll
      for (int jj = 0; jj < 4; ++jj) {
        int q = j*4 + jj;
        float da = ((const float*)&dA)[jj], db = ((const float*)&dB)[jj];
        float va = da * h0[0][gl][q] + agg[0][gl][q];
        float vb = db * h0[1][gl][q] + agg[1][gl][q];
        va = fmaxf(va * sc + sh, 0.f);
        vb = fmaxf(vb * sc + sh, 0.f);
        res[jj] = 0.5f * (va + vb);
      }
      if (CH == 0) {
        float4 o4;
        o4.x = 0.5f*res[0]; o4.y = 0.5f*res[1]; o4.z = 0.5f*res[2]; o4.w = 0.5f*res[3];
        *(float4*)(out + obase + (size_t)g*32 + i00) = o4;
      } else if (CH == 1) {
#pragma unroll
        for (int jj = 0; jj < 4; ++jj)
          out[obase + (size_t)(i00 + jj)*1024 + g] += 0.25f * res[jj];
      } else {
#pragma unroll
        for (int jj = 0; jj < 4; ++jj)
          out[obase + (size_t)(g >> 5)*1024 + (size_t)(i00 + jj)*32 + (g & 31)] += 0.25f * res[jj];
      }
    }
  }
}

extern "C" void kernel_launch(void* const* d_in, const int* in_sizes, int n_in,
                              void* d_out, int out_size, void* d_ws, size_t ws_size,
                              hipStream_t stream) {
  (void)in_sizes; (void)n_in; (void)out_size;
  const float* x    = (const float*)d_in[0];
  const int*   idx  = (const int*)d_in[1];
  const int*   adj1 = (const int*)d_in[2];
  const int*   adj2 = (const int*)d_in[3];
  const float *W[3], *e[3], *bb[3], *gm[3], *bt[3], *rm[3], *rv[3];
  for (int c = 0; c < 3; ++c) {
    int base = 4 + c*7;
    W[c]  = (const float*)d_in[base + 0];
    e[c]  = (const float*)d_in[base + 1];
    bb[c] = (const float*)d_in[base + 2];
    gm[c] = (const float*)d_in[base + 3];
    bt[c] = (const float*)d_in[base + 4];
    rm[c] = (const float*)d_in[base + 5];
    rv[c] = (const float*)d_in[base + 6];
  }
  char* ws = (char*)d_ws;
  unsigned short* wfrag  = (unsigned short*)ws;                    // 12 MB
  unsigned short* aofrag = (unsigned short*)(ws + 12582912);
  float* diagA  = (float*)(ws + 12607488);
  float* scale2 = (float*)(ws + 12608256);
  float* shift2 = (float*)(ws + 12620544);
  unsigned short* ximg = (unsigned short*)(ws + 16777216);         // 64 MB (CH0 A-image)
  bool img = ws_size >= (size_t)(16777216 + 67108864);

  prep_w<<<3072, 256, 0, stream>>>(W[0], W[1], W[2], wfrag);
  prep_misc<<<3, 256, 0, stream>>>(
      e[0], adj1, bb[0], gm[0], bt[0], rm[0], rv[0],
      e[1], adj2, bb[1], gm[1], bt[1], rm[1], rv[1],
      e[2], adj2, bb[2], gm[2], bt[2], rm[2], rv[2],
      aofrag, diagA, scale2, shift2);

  float* out = (float*)d_out;
  if (img) {
    prep_x<<<16384, 256, 0, stream>>>(x, idx, 0, ximg);
    gconv<0,1><<<2048, 256, 0, stream>>>(x, idx, wfrag, ximg, aofrag, diagA, scale2, shift2, out);
  } else {
    gconv<0,0><<<2048, 256, 0, stream>>>(x, idx, wfrag, ximg, aofrag, diagA, scale2, shift2, out);
  }
  gconv<1,0><<<2048, 256, 0, stream>>>(x, idx, wfrag + 2097152, ximg, aofrag + 4096,
                                       diagA + 64,  scale2 + 1024, shift2 + 1024, out);
  gconv<2,0><<<2048, 256, 0, stream>>>(x, idx, wfrag + 4194304, ximg, aofrag + 8192,
                                       diagA + 128, scale2 + 2048, shift2 + 2048, out);
}

// Round 7
// 558.552 us; speedup vs baseline: 3.1342x; 3.1342x over previous
//
#include <hip/hip_runtime.h>
#include <stdint.h>

typedef __attribute__((ext_vector_type(8))) short short8;
typedef __attribute__((ext_vector_type(16))) float f32x16;
typedef __attribute__((ext_vector_type(4))) float f32x4;
typedef __attribute__((ext_vector_type(4))) unsigned short ushort4v;

union S8 { short8 v; unsigned short u[8]; };

static __device__ __forceinline__ unsigned short f2bf(float f) {
  union { float f; unsigned u; } v; v.f = f;
  unsigned r = v.u + 0x7fffu + ((v.u >> 16) & 1u);
  return (unsigned short)(r >> 16);
}

static __device__ __forceinline__ void glds16(const void* g, void* l) {
  __builtin_amdgcn_global_load_lds(
      (const __attribute__((address_space(1))) unsigned int*)g,
      (__attribute__((address_space(3))) unsigned int*)l, 16, 0, 0);
}

// ---------------- prep: W -> glds-ready per-(g8,kt) 16KB images ----------------
// t = ((((c*8+g8)*32+kt)*2+ks)*8+tt)*64+lane ; tt = s*4+gt
// value = W_c[s][k = kt*32+ks*16+(lane>>5)*8+e][g = g8*128+gt*32+(lane&31)]
__global__ __launch_bounds__(256) void prep_w(const float* __restrict__ Wa,
                                              const float* __restrict__ Wb,
                                              const float* __restrict__ Wc,
                                              unsigned short* __restrict__ wfrag) {
  int t    = blockIdx.x * 256 + threadIdx.x;
  int lane = t & 63;
  int tt   = (t >> 6) & 7;
  int ks   = (t >> 9) & 1;
  int kt   = (t >> 10) & 31;
  int g8   = (t >> 15) & 7;
  int c    = t >> 18;
  const float* W = (c == 0) ? Wa : (c == 1) ? Wb : Wc;
  int s  = tt >> 2, gt = tt & 3;
  int g  = g8*128 + gt*32 + (lane & 31);
  int k0 = kt*32 + ks*16 + ((lane >> 5) * 8);
  const float* src = W + (size_t)s * 1048576 + (size_t)k0 * 1024 + g;
  unsigned short* dst = wfrag + (size_t)t * 8;
#pragma unroll
  for (int e = 0; e < 8; ++e) dst[e] = f2bf(src[(size_t)e * 1024]);
}

// ---------------- prep: x -> A-fragment image for one channel ----------------
// t = (((gid*32+kt)*2+ks)*2+h)*64+lane ; value = A[row = h*32 + (lane&31)][k]
__global__ __launch_bounds__(256) void prep_x(const float* __restrict__ x,
                                              const int* __restrict__ idxp,
                                              int c, unsigned short* __restrict__ ximg) {
  int t = blockIdx.x * 256 + threadIdx.x;
  int lane = t & 63;
  int h  = (t >> 6) & 1;
  int ks = (t >> 7) & 1;
  int kt = (t >> 8) & 31;
  int gid = t >> 13;
  int b = gid >> 3, v = gid & 7;
  int vv = h ? idxp[v] : v;
  const float* src = x + (size_t)(b*8 + vv) * 32768;
  int i = lane & 31;
  int k0 = kt*32 + ks*16 + ((lane >> 5) * 8);
  S8 pk;
  if (c == 0) {
#pragma unroll
    for (int e = 0; e < 8; ++e) pk.u[e] = f2bf(src[(size_t)(k0 + e)*32 + i]);
  } else {
    const float* sp = (c == 1) ? (src + i*1024 + k0)
                               : (src + (k0 >> 5)*1024 + i*32 + (k0 & 31));
    float4 u0 = *(const float4*)sp, u1 = *(const float4*)(sp + 4);
    pk.u[0]=f2bf(u0.x); pk.u[1]=f2bf(u0.y); pk.u[2]=f2bf(u0.z); pk.u[3]=f2bf(u0.w);
    pk.u[4]=f2bf(u1.x); pk.u[5]=f2bf(u1.y); pk.u[6]=f2bf(u1.z); pk.u[7]=f2bf(u1.w);
  }
  *(short8*)(ximg + (size_t)t * 8) = pk.v;
}

// ---------------- prep: softmax A, Aoff frags, diag, BN affine ----------------
__global__ __launch_bounds__(256) void prep_misc(
    const float* e0, const int* a0, const float* b0, const float* g0, const float* be0, const float* rm0, const float* rv0,
    const float* e1, const int* a1, const float* b1, const float* g1, const float* be1, const float* rm1, const float* rv1,
    const float* e2, const int* a2, const float* b2, const float* g2, const float* be2, const float* rm2, const float* rv2,
    unsigned short* __restrict__ aofrag, float* __restrict__ diagA,
    float* __restrict__ scale2, float* __restrict__ shift2) {
  __shared__ float A[64][64];
  int c = blockIdx.x;
  int tid = threadIdx.x;
  const float* ev = (c==0)?e0:(c==1)?e1:e2;
  const int*   ad = (c==0)?a0:(c==1)?a1:a2;
  const float* bb = (c==0)?b0:(c==1)?b1:b2;
  const float* gm = (c==0)?g0:(c==1)?g1:g2;
  const float* bt = (c==0)?be0:(c==1)?be1:be2;
  const float* rm = (c==0)?rm0:(c==1)?rm1:rm2;
  const float* rv = (c==0)?rv0:(c==1)?rv1:rv2;
  if (tid < 64) {
    int n = tid;
    float mx = -3.0e38f;
    for (int m = 0; m < 64; ++m) {
      float lg = (ad[n*64+m] > 0) ? ev[n*64+m] : -9.0e15f;
      A[n][m] = lg; mx = fmaxf(mx, lg);
    }
    float ssum = 0.f;
    for (int m = 0; m < 64; ++m) { float p = __expf(A[n][m] - mx); A[n][m] = p; ssum += p; }
    float inv = 1.f / ssum;
    for (int m = 0; m < 64; ++m) A[n][m] *= inv;
  }
  __syncthreads();
  if (tid < 64) diagA[c*64 + tid] = A[tid][tid];
  for (int idx = tid; idx < 4096; idx += 256) {
    int e  = idx & 7;
    int l  = (idx >> 3) & 63;
    int ks = (idx >> 9) & 3;
    int nt = idx >> 11;
    int n = nt*32 + (l & 31);
    int m = ks*16 + ((l >> 5) * 8) + e;
    float vv = (m == n) ? 0.f : A[n][m];
    aofrag[c*4096 + idx] = f2bf(vv);
  }
  for (int g = tid; g < 1024; g += 256) {
    float sc = gm[g] * rsqrtf(rv[g] + 1e-5f);
    scale2[c*1024 + g] = sc;
    shift2[c*1024 + g] = bt[g] + (bb[g] - rm[g]) * sc;
  }
}

// ---------------- fallback A loader (IMG=0 only) ----------------
template<int CH>
__device__ __forceinline__ void loadA(float av[2][8], const float* __restrict__ sview,
                                      int d0, int lh, int kt) {
#pragma unroll
  for (int ks = 0; ks < 2; ++ks) {
    int kb = kt*32 + ks*16 + lh*8;
    if (CH == 0) {
#pragma unroll
      for (int e = 0; e < 8; ++e) av[ks][e] = sview[(size_t)(kb + e)*32 + d0];
    } else if (CH == 1) {
      const float* sp = sview + d0*1024 + kb;
      *(float4*)&av[ks][0] = *(const float4*)sp;
      *(float4*)&av[ks][4] = *(const float4*)(sp + 4);
    } else {
      const float* sp = sview + kt*1024 + d0*32 + ks*16 + lh*8;
      *(float4*)&av[ks][0] = *(const float4*)sp;
      *(float4*)&av[ks][4] = *(const float4*)(sp + 4);
    }
  }
}

// ---------------- main fused channel kernel: pure-glds counted-vmcnt pipeline ----------------
// block: 128 m-rows (2 graphs) x [128 g x 2 s], BK=32, 32 k-steps
// LDS 64KB: B tribuf 3x16KB @0, A dbuf 2x8KB @49152. Epilogue reuses [0,64K).
template<int CH, int IMG>
__global__ __launch_bounds__(256, 2) void gconv(
    const float* __restrict__ x, const int* __restrict__ idxp,
    const unsigned short* __restrict__ wimg, const unsigned short* __restrict__ ximg,
    const unsigned short* __restrict__ aofrag,
    const float* __restrict__ diagA, const float* __restrict__ scale2,
    const float* __restrict__ shift2, float* __restrict__ out) {
  __shared__ alignas(128) char lds[65536];
  int tid = threadIdx.x, lane = tid & 63, wave = tid >> 6;
  int l31 = lane & 31, lh = lane >> 5;
  int wm = wave >> 1, sn = wave & 1;
  int bid = blockIdx.x;
  int g8 = bid & 7, mp = bid >> 3;
  int graphA = mp*2;
  int gid = graphA + wm;
  int b = gid >> 3, v = gid & 7;
  const float* sview = x + (size_t)(b*8 + (sn ? idxp[v] : v)) * 32768;  // IMG=0 only

  const char* srcB = (const char*)wimg + (size_t)g8 * 524288 + tid*16;
  const char* srcA = (const char*)ximg + (size_t)graphA * 131072 + tid*16;

  f32x16 acc[2][4];
#pragma unroll
  for (int mt = 0; mt < 2; ++mt)
#pragma unroll
    for (int gt = 0; gt < 4; ++gt)
#pragma unroll
      for (int r = 0; r < 16; ++r) acc[mt][gt][r] = 0.f;

  char* pB0 = lds;  char* pB1 = lds + 16384;  char* pB2 = lds + 32768;
  char* pA0 = lds + 49152;  char* pA1 = lds + 57344;
  int dW = wave * 1024;   // wave-uniform dest offset (glds adds lane*16)

  auto stageB = [&](char* dst, int kt) {
    const char* s = srcB + (size_t)kt * 16384;
#pragma unroll
    for (int j = 0; j < 4; ++j) glds16(s + j*4096, dst + dW + j*4096);
  };
  auto stageA = [&](char* dst, int kt) {
    const char* s = srcA + (size_t)kt * 4096;
    glds16(s, dst + dW);
    glds16(s + 131072, dst + 4096 + dW);
  };
  auto stageAfb = [&](char* dst, int kt) {   // IMG=0 fallback: reg-load + cvt + ds_write
    alignas(16) float av[2][8];
    loadA<CH>(av, sview, l31, lh, kt);
#pragma unroll
    for (int ks = 0; ks < 2; ++ks) {
      S8 pk;
#pragma unroll
      for (int e = 0; e < 8; ++e) pk.u[e] = f2bf(av[ks][e]);
      *(short8*)(dst + wm*4096 + (ks*2 + sn)*1024 + lane*16) = pk.v;
    }
  };
  auto compute = [&](const char* bB, const char* bA) {
    const char* bAx = bA + wm*4096;
    __builtin_amdgcn_s_setprio(1);
#pragma unroll
    for (int ks = 0; ks < 2; ++ks) {
      short8 a0 = *(const short8*)(bAx + (ks*2    )*1024 + lane*16);
      short8 a1 = *(const short8*)(bAx + (ks*2 + 1)*1024 + lane*16);
      const char* bp = bB + ((ks*8 + sn*4)*64 + lane)*16;
#pragma unroll
      for (int gt = 0; gt < 4; ++gt) {
        short8 bf = *(const short8*)(bp + gt*1024);
        acc[0][gt] = __builtin_amdgcn_mfma_f32_32x32x16_bf16(a0, bf, acc[0][gt], 0, 0, 0);
        acc[1][gt] = __builtin_amdgcn_mfma_f32_32x32x16_bf16(a1, bf, acc[1][gt], 0, 0, 0);
      }
    }
    __builtin_amdgcn_s_setprio(0);
  };

  // ---- prologue: A(0); B(0); B(1)  (issue-order fixed by sched_barriers) ----
  if (IMG) stageA(pA0, 0); else stageAfb(pA0, 0);
  __builtin_amdgcn_sched_barrier(0);
  stageB(pB0, 0);
  __builtin_amdgcn_sched_barrier(0);
  stageB(pB1, 1);
  __builtin_amdgcn_sched_barrier(0);

#pragma unroll 1
  for (int kt = 0; kt < 31; ++kt) {
    // queue at this point: B(kt)[4] A(kt)[2] B(kt+1)[4]  ->  vmcnt(4) retires B(kt)+A(kt)
    if (IMG) asm volatile("s_waitcnt vmcnt(4)" ::: "memory");
    else     asm volatile("s_waitcnt vmcnt(0) lgkmcnt(0)" ::: "memory");
    __builtin_amdgcn_s_barrier();
    if (IMG) stageA(pA1, kt + 1); else stageAfb(pA1, kt + 1);
    __builtin_amdgcn_sched_barrier(0);          // A-group strictly before B-group
    if (kt < 30) stageB(pB2, kt + 2);
    __builtin_amdgcn_sched_barrier(0);
    compute(pB0, pA0);
    { char* t = pB0; pB0 = pB1; pB1 = pB2; pB2 = t; }
    { char* t = pA0; pA0 = pA1; pA1 = t; }
  }
  asm volatile("s_waitcnt vmcnt(0) lgkmcnt(0)" ::: "memory");
  __builtin_amdgcn_s_barrier();
  compute(pB0, pA0);
  __syncthreads();

  // ---- epilogue (verified r4-r6 structure) ----
  if (sn == 1) {
    char* basep = lds + wm*16384;
#pragma unroll
    for (int gt = 0; gt < 4; ++gt) {
      int col = gt*32 + l31;
      char* cb = basep + col*128;
      int cs = (col & 7) << 4;
#pragma unroll
      for (int mt2 = 0; mt2 < 2; ++mt2)
#pragma unroll
        for (int j = 0; j < 4; ++j) {
          ushort4v pk;
          pk.x = f2bf(acc[mt2][gt][4*j+0]);
          pk.y = f2bf(acc[mt2][gt][4*j+1]);
          pk.z = f2bf(acc[mt2][gt][4*j+2]);
          pk.w = f2bf(acc[mt2][gt][4*j+3]);
          int r2 = mt2*64 + j*16 + lh*8;
          *(ushort4v*)(cb + (r2 ^ cs)) = pk;
        }
    }
  } else {
    char* ebase = lds + 32768 + wm*16384;
#pragma unroll
    for (int mt2 = 0; mt2 < 2; ++mt2)
#pragma unroll
      for (int t2 = 0; t2 < 2; ++t2)
#pragma unroll
        for (int q4 = 0; q4 < 4; ++q4)
          *(f32x4*)(ebase + (size_t)(((mt2*2 + t2)*4) + q4)*1024 + lane*16) =
              ((const f32x4*)&acc[mt2][2 + t2])[q4];
  }
  __syncthreads();

  f32x16 agg[2][2];
#pragma unroll
  for (int nta = 0; nta < 2; ++nta)
#pragma unroll
    for (int gl = 0; gl < 2; ++gl)
#pragma unroll
      for (int r = 0; r < 16; ++r) agg[nta][gl][r] = 0.f;

#pragma unroll
  for (int ks = 0; ks < 4; ++ks) {
#pragma unroll
    for (int gl = 0; gl < 2; ++gl) {
      int col = (sn*2 + gl)*32 + l31;
      int cs = (col & 7) << 4;
      short8 hf = *(const short8*)(lds + wm*16384 + col*128 + ((ks*32 + lh*16) ^ cs));
#pragma unroll
      for (int nta = 0; nta < 2; ++nta) {
        short8 aof = *(const short8*)((const char*)aofrag + (size_t)((nta*4 + ks)*64 + lane)*16);
        agg[nta][gl] = __builtin_amdgcn_mfma_f32_32x32x16_bf16(aof, hf, agg[nta][gl], 0, 0, 0);
      }
    }
  }

  f32x16 h0[2][2];
  if (sn == 0) {
    h0[0][0] = acc[0][0]; h0[0][1] = acc[0][1];
    h0[1][0] = acc[1][0]; h0[1][1] = acc[1][1];
  } else {
    const char* ebase = lds + 32768 + wm*16384;
#pragma unroll
    for (int mt2 = 0; mt2 < 2; ++mt2)
#pragma unroll
      for (int t2 = 0; t2 < 2; ++t2)
#pragma unroll
        for (int q4 = 0; q4 < 4; ++q4)
          ((f32x4*)&h0[mt2][t2])[q4] =
              *(const f32x4*)(ebase + (size_t)(((mt2*2 + t2)*4) + q4)*1024 + lane*16);
  }

  size_t obase = (size_t)gid * 32768;
#pragma unroll
  for (int gl = 0; gl < 2; ++gl) {
    int g = g8*128 + sn*64 + gl*32 + l31;
    float sc = scale2[g], sh = shift2[g];
#pragma unroll
    for (int j = 0; j < 4; ++j) {
      int i00 = j*8 + lh*4;
      float4 dA = *(const float4*)(diagA + i00);
      float4 dB = *(const float4*)(diagA + 32 + i00);
      float res[4];
#pragma unroll
      for (int jj = 0; jj < 4; ++jj) {
        int q = j*4 + jj;
        float da = ((const float*)&dA)[jj], db = ((const float*)&dB)[jj];
        float va = da * h0[0][gl][q] + agg[0][gl][q];
        float vb = db * h0[1][gl][q] + agg[1][gl][q];
        va = fmaxf(va * sc + sh, 0.f);
        vb = fmaxf(vb * sc + sh, 0.f);
        res[jj] = 0.5f * (va + vb);
      }
      if (CH == 0) {
        float4 o4;
        o4.x = 0.5f*res[0]; o4.y = 0.5f*res[1]; o4.z = 0.5f*res[2]; o4.w = 0.5f*res[3];
        *(float4*)(out + obase + (size_t)g*32 + i00) = o4;
      } else if (CH == 1) {
#pragma unroll
        for (int jj = 0; jj < 4; ++jj)
          out[obase + (size_t)(i00 + jj)*1024 + g] += 0.25f * res[jj];
      } else {
#pragma unroll
        for (int jj = 0; jj < 4; ++jj)
          out[obase + (size_t)(g >> 5)*1024 + (size_t)(i00 + jj)*32 + (g & 31)] += 0.25f * res[jj];
      }
    }
  }
}

extern "C" void kernel_launch(void* const* d_in, const int* in_sizes, int n_in,
                              void* d_out, int out_size, void* d_ws, size_t ws_size,
                              hipStream_t stream) {
  (void)in_sizes; (void)n_in; (void)out_size;
  const float* x    = (const float*)d_in[0];
  const int*   idx  = (const int*)d_in[1];
  const int*   adj1 = (const int*)d_in[2];
  const int*   adj2 = (const int*)d_in[3];
  const float *W[3], *e[3], *bb[3], *gm[3], *bt[3], *rm[3], *rv[3];
  for (int c = 0; c < 3; ++c) {
    int base = 4 + c*7;
    W[c]  = (const float*)d_in[base + 0];
    e[c]  = (const float*)d_in[base + 1];
    bb[c] = (const float*)d_in[base + 2];
    gm[c] = (const float*)d_in[base + 3];
    bt[c] = (const float*)d_in[base + 4];
    rm[c] = (const float*)d_in[base + 5];
    rv[c] = (const float*)d_in[base + 6];
  }
  char* ws = (char*)d_ws;
  unsigned short* wfrag  = (unsigned short*)ws;                    // 12 MB
  unsigned short* aofrag = (unsigned short*)(ws + 12582912);
  float* diagA  = (float*)(ws + 12607488);
  float* scale2 = (float*)(ws + 12608256);
  float* shift2 = (float*)(ws + 12620544);
  unsigned short* ximg = (unsigned short*)(ws + 16777216);         // 64 MB, reused per channel
  bool img = ws_size >= (size_t)(16777216 + 67108864);

  prep_w<<<3072, 256, 0, stream>>>(W[0], W[1], W[2], wfrag);
  prep_misc<<<3, 256, 0, stream>>>(
      e[0], adj1, bb[0], gm[0], bt[0], rm[0], rv[0],
      e[1], adj2, bb[1], gm[1], bt[1], rm[1], rv[1],
      e[2], adj2, bb[2], gm[2], bt[2], rm[2], rv[2],
      aofrag, diagA, scale2, shift2);

  float* out = (float*)d_out;
  if (img) {
    prep_x<<<16384, 256, 0, stream>>>(x, idx, 0, ximg);
    gconv<0,1><<<2048, 256, 0, stream>>>(x, idx, wfrag, ximg, aofrag,
                                         diagA, scale2, shift2, out);
    prep_x<<<16384, 256, 0, stream>>>(x, idx, 1, ximg);
    gconv<1,1><<<2048, 256, 0, stream>>>(x, idx, wfrag + 2097152, ximg, aofrag + 4096,
                                         diagA + 64,  scale2 + 1024, shift2 + 1024, out);
    prep_x<<<16384, 256, 0, stream>>>(x, idx, 2, ximg);
    gconv<2,1><<<2048, 256, 0, stream>>>(x, idx, wfrag + 4194304, ximg, aofrag + 8192,
                                         diagA + 128, scale2 + 2048, shift2 + 2048, out);
  } else {
    gconv<0,0><<<2048, 256, 0, stream>>>(x, idx, wfrag, ximg, aofrag,
                                         diagA, scale2, shift2, out);
    gconv<1,0><<<2048, 256, 0, stream>>>(x, idx, wfrag + 2097152, ximg, aofrag + 4096,
                                         diagA + 64,  scale2 + 1024, shift2 + 1024, out);
    gconv<2,0><<<2048, 256, 0, stream>>>(x, idx, wfrag + 4194304, ximg, aofrag + 8192,
                                         diagA + 128, scale2 + 2048, shift2 + 2048, out);
  }
}